// Round 10
// baseline (755.811 us; speedup 1.0000x reference)
//
#include <hip/hip_runtime.h>
#include <math.h>
#include <stdint.h>

#define TLEN 256
#define NB   32
#define HID  512
#define VOC  1024

typedef __attribute__((ext_vector_type(2))) __fp16  pk16_t;
typedef __attribute__((ext_vector_type(8))) _Float16 v8h;
typedef __attribute__((ext_vector_type(4))) float    v4f;

// ---- device-coherent (agent-scope) Z accessors ----
__device__ __forceinline__ float2 zload2(const float* p) {
    unsigned long long u = __hip_atomic_load((const unsigned long long*)p,
                                             __ATOMIC_RELAXED, __HIP_MEMORY_SCOPE_AGENT);
    union { unsigned long long u; float2 f; } c; c.u = u; return c.f;
}
__device__ __forceinline__ void zstore(float* p, float v) {
    __hip_atomic_store(p, v, __ATOMIC_RELAXED, __HIP_MEMORY_SCOPE_AGENT);
}
__device__ __forceinline__ uint32_t pack_pkrtz(float a, float b) {
    pk16_t h = __builtin_amdgcn_cvt_pkrtz(a, b);
    return __builtin_bit_cast(uint32_t, h);
}
__device__ __forceinline__ int udot4(uint32_t a, uint32_t b, int acc) {
#if __has_builtin(__builtin_amdgcn_udot4)
    return __builtin_amdgcn_udot4(a, b, acc, false);
#else
    return acc + (int)((a & 255u) * (b & 255u))
               + (int)(((a >> 8) & 255u) * ((b >> 8) & 255u))
               + (int)(((a >> 16) & 255u) * ((b >> 16) & 255u))
               + (int)((a >> 24) * (b >> 24));
#endif
}

// ---------------- GEMM v2: MFMA f16 16x16x32, 128x128 tile ----------------
// Double-buffered LDS, ONE barrier per K-iter. Measured round 5: cut the
// non-scan residual from ~148us to ~34us. Do not touch.
__global__ __launch_bounds__(256) void gemm_mfma(
    const float* __restrict__ A, const float* __restrict__ W,
    const float* __restrict__ bias, float* __restrict__ C)
{
    const int K = HID, N = VOC;
    __shared__ _Float16 As[2][128][40];
    __shared__ _Float16 Ws[2][128][40];
    int tid  = threadIdx.x;
    int wv   = tid >> 6;
    int lane = tid & 63;
    int wy = wv >> 1, wx = wv & 1;
    int quad = lane >> 4, l16 = lane & 15;
    int row0 = blockIdx.y << 7;
    int col0 = blockIdx.x << 7;

    v4f acc[4][4] = {};

    int sr = tid >> 1;
    int sk = (tid & 1) << 4;
    const float* ap = A + (size_t)(row0 + sr) * K + sk;
    const float* wp = W + (size_t)(col0 + sr) * K + sk;

    float4 a0 = *(const float4*)(ap);
    float4 a1 = *(const float4*)(ap + 4);
    float4 a2 = *(const float4*)(ap + 8);
    float4 a3 = *(const float4*)(ap + 12);
    float4 w0 = *(const float4*)(wp);
    float4 w1 = *(const float4*)(wp + 4);
    float4 w2 = *(const float4*)(wp + 8);
    float4 w3 = *(const float4*)(wp + 12);
    {
        uint32_t* ad = (uint32_t*)&As[0][sr][sk];
        ad[0] = pack_pkrtz(a0.x, a0.y); ad[1] = pack_pkrtz(a0.z, a0.w);
        ad[2] = pack_pkrtz(a1.x, a1.y); ad[3] = pack_pkrtz(a1.z, a1.w);
        ad[4] = pack_pkrtz(a2.x, a2.y); ad[5] = pack_pkrtz(a2.z, a2.w);
        ad[6] = pack_pkrtz(a3.x, a3.y); ad[7] = pack_pkrtz(a3.z, a3.w);
        uint32_t* wd = (uint32_t*)&Ws[0][sr][sk];
        wd[0] = pack_pkrtz(w0.x, w0.y); wd[1] = pack_pkrtz(w0.z, w0.w);
        wd[2] = pack_pkrtz(w1.x, w1.y); wd[3] = pack_pkrtz(w1.z, w1.w);
        wd[4] = pack_pkrtz(w2.x, w2.y); wd[5] = pack_pkrtz(w2.z, w2.w);
        wd[6] = pack_pkrtz(w3.x, w3.y); wd[7] = pack_pkrtz(w3.z, w3.w);
    }
    __syncthreads();

    const int NIT = K / 32;             // 16
    for (int i = 0; i < NIT; ++i) {
        int cur = i & 1, nxt = cur ^ 1;
        if (i + 1 < NIT) {
            const float* apn = ap + (i + 1) * 32;
            const float* wpn = wp + (i + 1) * 32;
            a0 = *(const float4*)(apn);
            a1 = *(const float4*)(apn + 4);
            a2 = *(const float4*)(apn + 8);
            a3 = *(const float4*)(apn + 12);
            w0 = *(const float4*)(wpn);
            w1 = *(const float4*)(wpn + 4);
            w2 = *(const float4*)(wpn + 8);
            w3 = *(const float4*)(wpn + 12);
        }
        v8h af[4], bf[4];
        #pragma unroll
        for (int r = 0; r < 4; ++r)
            af[r] = *(const v8h*)&As[cur][wy * 64 + r * 16 + l16][quad * 8];
        #pragma unroll
        for (int r = 0; r < 4; ++r)
            bf[r] = *(const v8h*)&Ws[cur][wx * 64 + r * 16 + l16][quad * 8];
        #pragma unroll
        for (int r = 0; r < 4; ++r)
            #pragma unroll
            for (int j = 0; j < 4; ++j)
                acc[r][j] = __builtin_amdgcn_mfma_f32_16x16x32_f16(af[r], bf[j], acc[r][j], 0, 0, 0);
        if (i + 1 < NIT) {
            uint32_t* ad = (uint32_t*)&As[nxt][sr][sk];
            ad[0] = pack_pkrtz(a0.x, a0.y); ad[1] = pack_pkrtz(a0.z, a0.w);
            ad[2] = pack_pkrtz(a1.x, a1.y); ad[3] = pack_pkrtz(a1.z, a1.w);
            ad[4] = pack_pkrtz(a2.x, a2.y); ad[5] = pack_pkrtz(a2.z, a2.w);
            ad[6] = pack_pkrtz(a3.x, a3.y); ad[7] = pack_pkrtz(a3.z, a3.w);
            uint32_t* wd = (uint32_t*)&Ws[nxt][sr][sk];
            wd[0] = pack_pkrtz(w0.x, w0.y); wd[1] = pack_pkrtz(w0.z, w0.w);
            wd[2] = pack_pkrtz(w1.x, w1.y); wd[3] = pack_pkrtz(w1.z, w1.w);
            wd[4] = pack_pkrtz(w2.x, w2.y); wd[5] = pack_pkrtz(w2.z, w2.w);
            wd[6] = pack_pkrtz(w3.x, w3.y); wd[7] = pack_pkrtz(w3.z, w3.w);
        }
        __syncthreads();
    }
    #pragma unroll
    for (int i = 0; i < 4; ++i) {
        #pragma unroll
        for (int j = 0; j < 4; ++j) {
            int ccol = col0 + wx * 64 + j * 16 + l16;
            float bb = bias[ccol];
            #pragma unroll
            for (int r = 0; r < 4; ++r) {
                int rrow = row0 + wy * 64 + i * 16 + quad * 4 + r;
                C[(size_t)rrow * N + ccol] = acc[i][j][r] + bb;
            }
        }
    }
}

// ---------------- persistent CRF scan v17c: fan-in 4, SPILL FIXED ----------------
// Byte-identical to v17b except __launch_bounds__(512, 2): round 9 showed the
// default occupancy target capped VGPRs at 128 while the kernel needs ~190
// (Ereg[128] + overhead) -> ~60 regs/thread spilled to scratch -> +99MB HBM
// traffic/step loop and scan 670us. 2 waves/EU raises the cap to 256; grid is
// 128 blocks over 256 CUs, so 1-block/CU occupancy is unchanged in practice.
__global__ __launch_bounds__(512, 2) void crf_scan(
    const float* __restrict__ logits, float* __restrict__ Za, float* __restrict__ Zb,
    float* __restrict__ Zfin,
    const float* __restrict__ trans, const int* __restrict__ lengths)
{
    __shared__ float Sred[2][8][64][5];   // [parity][wave][lane][4 cols + pad]
    __shared__ float Mred[2][8];          // [parity][wave] chunk maxes
    int tid  = threadIdx.x;
    int w    = tid >> 6;
    int lane = tid & 63;
    int b    = blockIdx.x;             // batch (group)
    int k    = blockIdx.y;             // column block: cols [k*256, k*256+256)

    int len = lengths[b];

    // E slice in VGPRs: Ereg[j+32*q] = u8x4 of exp(trans[w*128+4j+kk][cq])*196
    // for cols cq = k*256 + lane + 64*q, q=0..3.
    uint32_t Ereg[128];
    {
        const float* tc = trans + (k << 8) + lane;
        #pragma unroll
        for (int j = 0; j < 32; ++j) {
            int v0 = (w << 7) + (j << 2);
            #pragma unroll
            for (int q = 0; q < 4; ++q) {
                const float* tq = tc + (q << 6);
                float a0 = __expf(tq[(size_t)(v0 + 0) << 10]) * 196.f;
                float a1 = __expf(tq[(size_t)(v0 + 1) << 10]) * 196.f;
                float a2 = __expf(tq[(size_t)(v0 + 2) << 10]) * 196.f;
                float a3 = __expf(tq[(size_t)(v0 + 3) << 10]) * 196.f;
                uint32_t q0 = (uint32_t)__float2uint_rn(fminf(a0, 255.f));
                uint32_t q1 = (uint32_t)__float2uint_rn(fminf(a1, 255.f));
                uint32_t q2 = (uint32_t)__float2uint_rn(fminf(a2, 255.f));
                uint32_t q3 = (uint32_t)__float2uint_rn(fminf(a3, 255.f));
                Ereg[j + (q << 5)] = q0 | (q1 << 8) | (q2 << 16) | (q3 << 24);
            }
        }
    }

    // prologue: len==1 freezes at Z0 = logits[0]; else prefetch fin for t=1
    float finv = 0.f;
    if (tid < 256) {
        int c = (k << 8) + tid;
        if (len == 1) Zfin[(size_t)b * VOC + c] = logits[(size_t)b * VOC + c];
        else          finv = logits[(size_t)(NB + b) * VOC + c];   // logits[t=1]
    }

    const bool loader = (lane < 32);
    // loader lane covers v = w*128 + lane*4 .. +3 (producer block = w>>1)
    const size_t zoff = (size_t)b * VOC + (size_t)((w << 7) + (lane << 2));
    float2 zlo = {0.f, 0.f}, zhi = {0.f, 0.f};

    for (int t = 1; t < len; ++t) {
        int par = t & 1;
        // (A) stage Z_{t-1}: poll self-validating tagged words, sleep backoff,
        //     bounded budget (anti-hang diagnostic; never hit in normal runs)
        if (t == 1) {
            if (loader) {
                const float* zp = logits + zoff;    // Z0 = logits[0], kernel-ordered
                zlo = *(const float2*)zp;
                zhi = *(const float2*)(zp + 2);
            }
        } else if (loader) {
            const float* zp = ((t & 1) ? Zb : Za) + zoff;   // src = dst(t-1)
            unsigned tg = 8u | (unsigned)((t - 1) & 7);
            int budget = 1 << 16;
            for (;;) {
                float2 a = zload2(zp);
                float2 bb = zload2(zp + 2);
                unsigned x0 = __builtin_bit_cast(unsigned, a.x) & 15u;
                unsigned x1 = __builtin_bit_cast(unsigned, a.y) & 15u;
                unsigned x2 = __builtin_bit_cast(unsigned, bb.x) & 15u;
                unsigned x3 = __builtin_bit_cast(unsigned, bb.y) & 15u;
                if (((x0 ^ tg) | (x1 ^ tg) | (x2 ^ tg) | (x3 ^ tg)) == 0u) {
                    zlo = a; zhi = bb; break;
                }
                if (--budget == 0) { zlo = a; zhi = bb; break; }   // diagnostic
                __builtin_amdgcn_s_sleep(1);
            }
        }

        // (B) chunk max over 128 v (32 loader lanes x 4) + quantize
        float m = loader ? fmaxf(fmaxf(zlo.x, zlo.y), fmaxf(zhi.x, zhi.y)) : -3.0e38f;
        #pragma unroll
        for (int off = 16; off; off >>= 1) m = fmaxf(m, __shfl_xor(m, off));
        if (lane == 0) Mred[par][w] = m;
        uint32_t pp = 0;
        if (loader) {
            uint32_t q0 = (uint32_t)__float2uint_rn(__expf(zlo.x - m) * 255.f);
            uint32_t q1 = (uint32_t)__float2uint_rn(__expf(zlo.y - m) * 255.f);
            uint32_t q2 = (uint32_t)__float2uint_rn(__expf(zhi.x - m) * 255.f);
            uint32_t q3 = (uint32_t)__float2uint_rn(__expf(zhi.y - m) * 255.f);
            pp = q0 | (q1 << 8) | (q2 << 16) | (q3 << 24);
        }

        // (C) 32 v4-rows x 4 cols, E from registers; p broadcast via readlane
        int acc0 = 0, acc1 = 0, acc2 = 0, acc3 = 0;
        #pragma unroll
        for (int j = 0; j < 32; j += 2) {
            uint32_t s0 = (uint32_t)__builtin_amdgcn_readlane((int)pp, j);
            uint32_t s1 = (uint32_t)__builtin_amdgcn_readlane((int)pp, j + 1);
            acc0 = udot4(Ereg[j],      s0, acc0);
            acc1 = udot4(Ereg[j + 32], s0, acc1);
            acc2 = udot4(Ereg[j + 64], s0, acc2);
            acc3 = udot4(Ereg[j + 96], s0, acc3);
            acc0 = udot4(Ereg[j + 1],  s1, acc0);
            acc1 = udot4(Ereg[j + 33], s1, acc1);
            acc2 = udot4(Ereg[j + 65], s1, acc2);
            acc3 = udot4(Ereg[j + 97], s1, acc3);
        }
        Sred[par][w][lane][0] = (float)acc0;
        Sred[par][w][lane][1] = (float)acc1;
        Sred[par][w][lane][2] = (float)acc2;
        Sred[par][w][lane][3] = (float)acc3;
        __syncthreads();                  // the ONLY barrier per step

        // (D) finalize + tagged store + fin(t+1) prefetch
        if (tid < 256) {
            float M = Mred[par][0];
            #pragma unroll
            for (int ww = 1; ww < 8; ++ww) M = fmaxf(M, Mred[par][ww]);
            int l = tid & 63, hc = tid >> 6;
            float S = 0.f;
            #pragma unroll
            for (int ww = 0; ww < 8; ++ww)
                S += __expf(Mred[par][ww] - M) * Sred[par][ww][l][hc];
            int c = (k << 8) + tid;
            float outv = finv + M + __logf(S * (1.0f / (255.f * 196.f)));
            if (t < len - 1) {
                float* dst = (t & 1) ? Za : Zb;
                unsigned ub = (__builtin_bit_cast(unsigned, outv) & ~15u)
                            | 8u | (unsigned)(t & 7);
                zstore(&dst[(size_t)b * VOC + c], __builtin_bit_cast(float, ub));
                finv = logits[((size_t)(t + 1) * NB + b) * VOC + c];
            } else {
                Zfin[(size_t)b * VOC + c] = outv;   // final value, untagged
            }
        }
        // next iteration writes parity^1 -> no trailing barrier needed
    }
}

// ---------------- epilogue: one block per batch, atomicAdd combine ----------------
__global__ __launch_bounds__(256) void crf_finish2(
    const float* __restrict__ Zfin, const float* __restrict__ logits,
    const float* __restrict__ trans, const int* __restrict__ targets,
    const int* __restrict__ lengths, float* __restrict__ out)
{
    __shared__ float redm[4], reds[4], reda[4];
    int b = blockIdx.x;
    int tid = threadIdx.x;
    int lane = tid & 63, wv = tid >> 6;
    const float* zr = Zfin + (size_t)b * VOC;

    float m = -1e30f;
    #pragma unroll
    for (int i = 0; i < 4; ++i) m = fmaxf(m, zr[tid + (i << 8)]);
    #pragma unroll
    for (int off = 32; off; off >>= 1) m = fmaxf(m, __shfl_xor(m, off));
    if (lane == 0) redm[wv] = m;
    __syncthreads();
    m = fmaxf(fmaxf(redm[0], redm[1]), fmaxf(redm[2], redm[3]));

    float s = 0.f;
    #pragma unroll
    for (int i = 0; i < 4; ++i) s += __expf(zr[tid + (i << 8)] - m);
    #pragma unroll
    for (int off = 32; off; off >>= 1) s += __shfl_xor(s, off);
    if (lane == 0) reds[wv] = s;

    int len = lengths[b];
    float acc = 0.f;
    int t = tid;
    if (t < len) {
        int tg = targets[t * NB + b];
        acc = logits[((size_t)t * NB + b) * VOC + tg];
        if (t >= 1) acc += trans[(size_t)targets[(t - 1) * NB + b] * VOC + tg];
    }
    #pragma unroll
    for (int off = 32; off; off >>= 1) acc += __shfl_xor(acc, off);
    if (lane == 0) reda[wv] = acc;
    __syncthreads();

    if (tid == 0) {
        float S = reds[0] + reds[1] + reds[2] + reds[3];
        float logZ = m + __logf(S);
        float score = reda[0] + reda[1] + reda[2] + reda[3];
        atomicAdd(out, (logZ - score) * (1.0f / NB));
    }
}

extern "C" void kernel_launch(void* const* d_in, const int* in_sizes, int n_in,
                              void* d_out, int out_size, void* d_ws, size_t ws_size,
                              hipStream_t stream)
{
    const float* enc   = (const float*)d_in[0];
    const float* W     = (const float*)d_in[1];
    const float* bias  = (const float*)d_in[2];
    const float* trans = (const float*)d_in[3];
    const int* targets = (const int*)d_in[4];
    const int* lengths = (const int*)d_in[5];
    float* out = (float*)d_out;

    // ws: logits 33.5MB | Za 128KB | Zb 128KB | Zfin 128KB
    float* ws     = (float*)d_ws;
    float* logits = ws;
    float* Za     = logits + (size_t)TLEN * NB * VOC;
    float* Zb     = Za + (size_t)NB * VOC;
    float* Zfin   = Zb + (size_t)NB * VOC;

    // tags live in Z words: zero-init (nibble 0 unreachable as a tag; also
    // clears stale tag-bearing data from a previous run of this graph)
    (void)hipMemsetAsync(Za, 0, 2 * (size_t)NB * VOC * sizeof(float), stream);
    (void)hipMemsetAsync(out, 0, sizeof(float), stream);
    gemm_mfma<<<dim3(VOC / 128, TLEN * NB / 128), 256, 0, stream>>>(enc, W, bias, logits);
    crf_scan<<<dim3(NB, 4), 512, 0, stream>>>(logits, Za, Zb, Zfin, trans, lengths);
    crf_finish2<<<NB, 256, 0, stream>>>(Zfin, logits, trans, targets, lengths, out);
}

// Round 11
// 745.118 us; speedup vs baseline: 1.0143x; 1.0143x over previous
//
#include <hip/hip_runtime.h>
#include <math.h>
#include <stdint.h>

#define TLEN 256
#define NB   32
#define HID  512
#define VOC  1024

typedef __attribute__((ext_vector_type(2))) __fp16  pk16_t;
typedef __attribute__((ext_vector_type(8))) _Float16 v8h;
typedef __attribute__((ext_vector_type(4))) float    v4f;

// ---- device-coherent (agent-scope) Z accessors ----
__device__ __forceinline__ float2 zload2(const float* p) {
    unsigned long long u = __hip_atomic_load((const unsigned long long*)p,
                                             __ATOMIC_RELAXED, __HIP_MEMORY_SCOPE_AGENT);
    union { unsigned long long u; float2 f; } c; c.u = u; return c.f;
}
__device__ __forceinline__ void zstore(float* p, float v) {
    __hip_atomic_store(p, v, __ATOMIC_RELAXED, __HIP_MEMORY_SCOPE_AGENT);
}
__device__ __forceinline__ uint32_t pack_pkrtz(float a, float b) {
    pk16_t h = __builtin_amdgcn_cvt_pkrtz(a, b);
    return __builtin_bit_cast(uint32_t, h);
}
__device__ __forceinline__ int udot4(uint32_t a, uint32_t b, int acc) {
#if __has_builtin(__builtin_amdgcn_udot4)
    return __builtin_amdgcn_udot4(a, b, acc, false);
#else
    return acc + (int)((a & 255u) * (b & 255u))
               + (int)(((a >> 8) & 255u) * ((b >> 8) & 255u))
               + (int)(((a >> 16) & 255u) * ((b >> 16) & 255u))
               + (int)((a >> 24) * (b >> 24));
#endif
}

// ---------------- GEMM v2: MFMA f16 16x16x32, 128x128 tile ----------------
// Double-buffered LDS, ONE barrier per K-iter. Measured round 5: cut the
// non-scan residual from ~148us to ~34us. Do not touch.
__global__ __launch_bounds__(256) void gemm_mfma(
    const float* __restrict__ A, const float* __restrict__ W,
    const float* __restrict__ bias, float* __restrict__ C)
{
    const int K = HID, N = VOC;
    __shared__ _Float16 As[2][128][40];
    __shared__ _Float16 Ws[2][128][40];
    int tid  = threadIdx.x;
    int wv   = tid >> 6;
    int lane = tid & 63;
    int wy = wv >> 1, wx = wv & 1;
    int quad = lane >> 4, l16 = lane & 15;
    int row0 = blockIdx.y << 7;
    int col0 = blockIdx.x << 7;

    v4f acc[4][4] = {};

    int sr = tid >> 1;
    int sk = (tid & 1) << 4;
    const float* ap = A + (size_t)(row0 + sr) * K + sk;
    const float* wp = W + (size_t)(col0 + sr) * K + sk;

    float4 a0 = *(const float4*)(ap);
    float4 a1 = *(const float4*)(ap + 4);
    float4 a2 = *(const float4*)(ap + 8);
    float4 a3 = *(const float4*)(ap + 12);
    float4 w0 = *(const float4*)(wp);
    float4 w1 = *(const float4*)(wp + 4);
    float4 w2 = *(const float4*)(wp + 8);
    float4 w3 = *(const float4*)(wp + 12);
    {
        uint32_t* ad = (uint32_t*)&As[0][sr][sk];
        ad[0] = pack_pkrtz(a0.x, a0.y); ad[1] = pack_pkrtz(a0.z, a0.w);
        ad[2] = pack_pkrtz(a1.x, a1.y); ad[3] = pack_pkrtz(a1.z, a1.w);
        ad[4] = pack_pkrtz(a2.x, a2.y); ad[5] = pack_pkrtz(a2.z, a2.w);
        ad[6] = pack_pkrtz(a3.x, a3.y); ad[7] = pack_pkrtz(a3.z, a3.w);
        uint32_t* wd = (uint32_t*)&Ws[0][sr][sk];
        wd[0] = pack_pkrtz(w0.x, w0.y); wd[1] = pack_pkrtz(w0.z, w0.w);
        wd[2] = pack_pkrtz(w1.x, w1.y); wd[3] = pack_pkrtz(w1.z, w1.w);
        wd[4] = pack_pkrtz(w2.x, w2.y); wd[5] = pack_pkrtz(w2.z, w2.w);
        wd[6] = pack_pkrtz(w3.x, w3.y); wd[7] = pack_pkrtz(w3.z, w3.w);
    }
    __syncthreads();

    const int NIT = K / 32;             // 16
    for (int i = 0; i < NIT; ++i) {
        int cur = i & 1, nxt = cur ^ 1;
        if (i + 1 < NIT) {
            const float* apn = ap + (i + 1) * 32;
            const float* wpn = wp + (i + 1) * 32;
            a0 = *(const float4*)(apn);
            a1 = *(const float4*)(apn + 4);
            a2 = *(const float4*)(apn + 8);
            a3 = *(const float4*)(apn + 12);
            w0 = *(const float4*)(wpn);
            w1 = *(const float4*)(wpn + 4);
            w2 = *(const float4*)(wpn + 8);
            w3 = *(const float4*)(wpn + 12);
        }
        v8h af[4], bf[4];
        #pragma unroll
        for (int r = 0; r < 4; ++r)
            af[r] = *(const v8h*)&As[cur][wy * 64 + r * 16 + l16][quad * 8];
        #pragma unroll
        for (int r = 0; r < 4; ++r)
            bf[r] = *(const v8h*)&Ws[cur][wx * 64 + r * 16 + l16][quad * 8];
        #pragma unroll
        for (int r = 0; r < 4; ++r)
            #pragma unroll
            for (int j = 0; j < 4; ++j)
                acc[r][j] = __builtin_amdgcn_mfma_f32_16x16x32_f16(af[r], bf[j], acc[r][j], 0, 0, 0);
        if (i + 1 < NIT) {
            uint32_t* ad = (uint32_t*)&As[nxt][sr][sk];
            ad[0] = pack_pkrtz(a0.x, a0.y); ad[1] = pack_pkrtz(a0.z, a0.w);
            ad[2] = pack_pkrtz(a1.x, a1.y); ad[3] = pack_pkrtz(a1.z, a1.w);
            ad[4] = pack_pkrtz(a2.x, a2.y); ad[5] = pack_pkrtz(a2.z, a2.w);
            ad[6] = pack_pkrtz(a3.x, a3.y); ad[7] = pack_pkrtz(a3.z, a3.w);
            uint32_t* wd = (uint32_t*)&Ws[nxt][sr][sk];
            wd[0] = pack_pkrtz(w0.x, w0.y); wd[1] = pack_pkrtz(w0.z, w0.w);
            wd[2] = pack_pkrtz(w1.x, w1.y); wd[3] = pack_pkrtz(w1.z, w1.w);
            wd[4] = pack_pkrtz(w2.x, w2.y); wd[5] = pack_pkrtz(w2.z, w2.w);
            wd[6] = pack_pkrtz(w3.x, w3.y); wd[7] = pack_pkrtz(w3.z, w3.w);
        }
        __syncthreads();
    }
    #pragma unroll
    for (int i = 0; i < 4; ++i) {
        #pragma unroll
        for (int j = 0; j < 4; ++j) {
            int ccol = col0 + wx * 64 + j * 16 + l16;
            float bb = bias[ccol];
            #pragma unroll
            for (int r = 0; r < 4; ++r) {
                int rrow = row0 + wy * 64 + i * 16 + quad * 4 + r;
                C[(size_t)rrow * N + ccol] = acc[i][j][r] + bb;
            }
        }
    }
}

// ---------------- persistent CRF scan v17d: fan-in 4, SROA-safe E arrays ----------------
// Round 9/10 diagnosis: Ereg[128] exceeded the scalarization (SROA) limit ->
// the array lived in SCRATCH from the IR level (VGPR_Count pinned at 128,
// +63MB spill WRITE traffic) — launch_bounds couldn't help because the values
// never became registers. v16's Ereg[64] DID scalarize. Fix: four named
// 32-entry arrays (each well under the limit), everything else identical.
// __launch_bounds__(512,2) gives the allocator room for the ~190 real regs.
__global__ __launch_bounds__(512, 2) void crf_scan(
    const float* __restrict__ logits, float* __restrict__ Za, float* __restrict__ Zb,
    float* __restrict__ Zfin,
    const float* __restrict__ trans, const int* __restrict__ lengths)
{
    __shared__ float Sred[2][8][64][5];   // [parity][wave][lane][4 cols + pad]
    __shared__ float Mred[2][8];          // [parity][wave] chunk maxes
    int tid  = threadIdx.x;
    int w    = tid >> 6;
    int lane = tid & 63;
    int b    = blockIdx.x;             // batch (group)
    int k    = blockIdx.y;             // column block: cols [k*256, k*256+256)

    int len = lengths[b];

    // E slices in VGPRs, one 32-entry array per owned column:
    // EregQ[j] = u8x4 of exp(trans[w*128+4j+kk][cq])*196, cq = k*256+lane+64*q
    uint32_t EregA[32], EregB[32], EregC[32], EregD[32];
    {
        const float* tc = trans + (k << 8) + lane;
        #pragma unroll
        for (int j = 0; j < 32; ++j) {
            int v0 = (w << 7) + (j << 2);
            #pragma unroll
            for (int q = 0; q < 4; ++q) {
                const float* tq = tc + (q << 6);
                float a0 = __expf(tq[(size_t)(v0 + 0) << 10]) * 196.f;
                float a1 = __expf(tq[(size_t)(v0 + 1) << 10]) * 196.f;
                float a2 = __expf(tq[(size_t)(v0 + 2) << 10]) * 196.f;
                float a3 = __expf(tq[(size_t)(v0 + 3) << 10]) * 196.f;
                uint32_t q0 = (uint32_t)__float2uint_rn(fminf(a0, 255.f));
                uint32_t q1 = (uint32_t)__float2uint_rn(fminf(a1, 255.f));
                uint32_t q2 = (uint32_t)__float2uint_rn(fminf(a2, 255.f));
                uint32_t q3 = (uint32_t)__float2uint_rn(fminf(a3, 255.f));
                uint32_t pk = q0 | (q1 << 8) | (q2 << 16) | (q3 << 24);
                if      (q == 0) EregA[j] = pk;
                else if (q == 1) EregB[j] = pk;
                else if (q == 2) EregC[j] = pk;
                else             EregD[j] = pk;
            }
        }
    }

    // prologue: len==1 freezes at Z0 = logits[0]; else prefetch fin for t=1
    float finv = 0.f;
    if (tid < 256) {
        int c = (k << 8) + tid;
        if (len == 1) Zfin[(size_t)b * VOC + c] = logits[(size_t)b * VOC + c];
        else          finv = logits[(size_t)(NB + b) * VOC + c];   // logits[t=1]
    }

    const bool loader = (lane < 32);
    // loader lane covers v = w*128 + lane*4 .. +3 (producer block = w>>1)
    const size_t zoff = (size_t)b * VOC + (size_t)((w << 7) + (lane << 2));
    float2 zlo = {0.f, 0.f}, zhi = {0.f, 0.f};

    for (int t = 1; t < len; ++t) {
        int par = t & 1;
        // (A) stage Z_{t-1}: poll self-validating tagged words, sleep backoff,
        //     bounded budget (anti-hang diagnostic; never hit in normal runs)
        if (t == 1) {
            if (loader) {
                const float* zp = logits + zoff;    // Z0 = logits[0], kernel-ordered
                zlo = *(const float2*)zp;
                zhi = *(const float2*)(zp + 2);
            }
        } else if (loader) {
            const float* zp = ((t & 1) ? Zb : Za) + zoff;   // src = dst(t-1)
            unsigned tg = 8u | (unsigned)((t - 1) & 7);
            int budget = 1 << 16;
            for (;;) {
                float2 a = zload2(zp);
                float2 bb = zload2(zp + 2);
                unsigned x0 = __builtin_bit_cast(unsigned, a.x) & 15u;
                unsigned x1 = __builtin_bit_cast(unsigned, a.y) & 15u;
                unsigned x2 = __builtin_bit_cast(unsigned, bb.x) & 15u;
                unsigned x3 = __builtin_bit_cast(unsigned, bb.y) & 15u;
                if (((x0 ^ tg) | (x1 ^ tg) | (x2 ^ tg) | (x3 ^ tg)) == 0u) {
                    zlo = a; zhi = bb; break;
                }
                if (--budget == 0) { zlo = a; zhi = bb; break; }   // diagnostic
                __builtin_amdgcn_s_sleep(1);
            }
        }

        // (B) chunk max over 128 v (32 loader lanes x 4) + quantize
        float m = loader ? fmaxf(fmaxf(zlo.x, zlo.y), fmaxf(zhi.x, zhi.y)) : -3.0e38f;
        #pragma unroll
        for (int off = 16; off; off >>= 1) m = fmaxf(m, __shfl_xor(m, off));
        if (lane == 0) Mred[par][w] = m;
        uint32_t pp = 0;
        if (loader) {
            uint32_t q0 = (uint32_t)__float2uint_rn(__expf(zlo.x - m) * 255.f);
            uint32_t q1 = (uint32_t)__float2uint_rn(__expf(zlo.y - m) * 255.f);
            uint32_t q2 = (uint32_t)__float2uint_rn(__expf(zhi.x - m) * 255.f);
            uint32_t q3 = (uint32_t)__float2uint_rn(__expf(zhi.y - m) * 255.f);
            pp = q0 | (q1 << 8) | (q2 << 16) | (q3 << 24);
        }

        // (C) 32 v4-rows x 4 cols, E from registers; p broadcast via readlane
        int acc0 = 0, acc1 = 0, acc2 = 0, acc3 = 0;
        #pragma unroll
        for (int j = 0; j < 32; j += 2) {
            uint32_t s0 = (uint32_t)__builtin_amdgcn_readlane((int)pp, j);
            uint32_t s1 = (uint32_t)__builtin_amdgcn_readlane((int)pp, j + 1);
            acc0 = udot4(EregA[j], s0, acc0);
            acc1 = udot4(EregB[j], s0, acc1);
            acc2 = udot4(EregC[j], s0, acc2);
            acc3 = udot4(EregD[j], s0, acc3);
            acc0 = udot4(EregA[j + 1], s1, acc0);
            acc1 = udot4(EregB[j + 1], s1, acc1);
            acc2 = udot4(EregC[j + 1], s1, acc2);
            acc3 = udot4(EregD[j + 1], s1, acc3);
        }
        Sred[par][w][lane][0] = (float)acc0;
        Sred[par][w][lane][1] = (float)acc1;
        Sred[par][w][lane][2] = (float)acc2;
        Sred[par][w][lane][3] = (float)acc3;
        __syncthreads();                  // the ONLY barrier per step

        // (D) finalize + tagged store + fin(t+1) prefetch
        if (tid < 256) {
            float M = Mred[par][0];
            #pragma unroll
            for (int ww = 1; ww < 8; ++ww) M = fmaxf(M, Mred[par][ww]);
            int l = tid & 63, hc = tid >> 6;
            float S = 0.f;
            #pragma unroll
            for (int ww = 0; ww < 8; ++ww)
                S += __expf(Mred[par][ww] - M) * Sred[par][ww][l][hc];
            int c = (k << 8) + tid;
            float outv = finv + M + __logf(S * (1.0f / (255.f * 196.f)));
            if (t < len - 1) {
                float* dst = (t & 1) ? Za : Zb;
                unsigned ub = (__builtin_bit_cast(unsigned, outv) & ~15u)
                            | 8u | (unsigned)(t & 7);
                zstore(&dst[(size_t)b * VOC + c], __builtin_bit_cast(float, ub));
                finv = logits[((size_t)(t + 1) * NB + b) * VOC + c];
            } else {
                Zfin[(size_t)b * VOC + c] = outv;   // final value, untagged
            }
        }
        // next iteration writes parity^1 -> no trailing barrier needed
    }
}

// ---------------- epilogue: one block per batch, atomicAdd combine ----------------
__global__ __launch_bounds__(256) void crf_finish2(
    const float* __restrict__ Zfin, const float* __restrict__ logits,
    const float* __restrict__ trans, const int* __restrict__ targets,
    const int* __restrict__ lengths, float* __restrict__ out)
{
    __shared__ float redm[4], reds[4], reda[4];
    int b = blockIdx.x;
    int tid = threadIdx.x;
    int lane = tid & 63, wv = tid >> 6;
    const float* zr = Zfin + (size_t)b * VOC;

    float m = -1e30f;
    #pragma unroll
    for (int i = 0; i < 4; ++i) m = fmaxf(m, zr[tid + (i << 8)]);
    #pragma unroll
    for (int off = 32; off; off >>= 1) m = fmaxf(m, __shfl_xor(m, off));
    if (lane == 0) redm[wv] = m;
    __syncthreads();
    m = fmaxf(fmaxf(redm[0], redm[1]), fmaxf(redm[2], redm[3]));

    float s = 0.f;
    #pragma unroll
    for (int i = 0; i < 4; ++i) s += __expf(zr[tid + (i << 8)] - m);
    #pragma unroll
    for (int off = 32; off; off >>= 1) s += __shfl_xor(s, off);
    if (lane == 0) reds[wv] = s;

    int len = lengths[b];
    float acc = 0.f;
    int t = tid;
    if (t < len) {
        int tg = targets[t * NB + b];
        acc = logits[((size_t)t * NB + b) * VOC + tg];
        if (t >= 1) acc += trans[(size_t)targets[(t - 1) * NB + b] * VOC + tg];
    }
    #pragma unroll
    for (int off = 32; off; off >>= 1) acc += __shfl_xor(acc, off);
    if (lane == 0) reda[wv] = acc;
    __syncthreads();

    if (tid == 0) {
        float S = reds[0] + reds[1] + reds[2] + reds[3];
        float logZ = m + __logf(S);
        float score = reda[0] + reda[1] + reda[2] + reda[3];
        atomicAdd(out, (logZ - score) * (1.0f / NB));
    }
}

extern "C" void kernel_launch(void* const* d_in, const int* in_sizes, int n_in,
                              void* d_out, int out_size, void* d_ws, size_t ws_size,
                              hipStream_t stream)
{
    const float* enc   = (const float*)d_in[0];
    const float* W     = (const float*)d_in[1];
    const float* bias  = (const float*)d_in[2];
    const float* trans = (const float*)d_in[3];
    const int* targets = (const int*)d_in[4];
    const int* lengths = (const int*)d_in[5];
    float* out = (float*)d_out;

    // ws: logits 33.5MB | Za 128KB | Zb 128KB | Zfin 128KB
    float* ws     = (float*)d_ws;
    float* logits = ws;
    float* Za     = logits + (size_t)TLEN * NB * VOC;
    float* Zb     = Za + (size_t)NB * VOC;
    float* Zfin   = Zb + (size_t)NB * VOC;

    // tags live in Z words: zero-init (nibble 0 unreachable as a tag; also
    // clears stale tag-bearing data from a previous run of this graph)
    (void)hipMemsetAsync(Za, 0, 2 * (size_t)NB * VOC * sizeof(float), stream);
    (void)hipMemsetAsync(out, 0, sizeof(float), stream);
    gemm_mfma<<<dim3(VOC / 128, TLEN * NB / 128), 256, 0, stream>>>(enc, W, bias, logits);
    crf_scan<<<dim3(NB, 4), 512, 0, stream>>>(logits, Za, Zb, Zfin, trans, lengths);
    crf_finish2<<<NB, 256, 0, stream>>>(Zfin, logits, trans, targets, lengths, out);
}

// Round 12
// 743.831 us; speedup vs baseline: 1.0161x; 1.0017x over previous
//
#include <hip/hip_runtime.h>
#include <math.h>
#include <stdint.h>

#define TLEN 256
#define NB   32
#define HID  512
#define VOC  1024

typedef __attribute__((ext_vector_type(2))) __fp16  pk16_t;
typedef __attribute__((ext_vector_type(8))) _Float16 v8h;
typedef __attribute__((ext_vector_type(4))) float    v4f;

// ---- device-coherent (agent-scope) Z accessors ----
__device__ __forceinline__ float2 zload2(const float* p) {
    unsigned long long u = __hip_atomic_load((const unsigned long long*)p,
                                             __ATOMIC_RELAXED, __HIP_MEMORY_SCOPE_AGENT);
    union { unsigned long long u; float2 f; } c; c.u = u; return c.f;
}
__device__ __forceinline__ void zstore(float* p, float v) {
    __hip_atomic_store(p, v, __ATOMIC_RELAXED, __HIP_MEMORY_SCOPE_AGENT);
}
__device__ __forceinline__ uint32_t pack_pkrtz(float a, float b) {
    pk16_t h = __builtin_amdgcn_cvt_pkrtz(a, b);
    return __builtin_bit_cast(uint32_t, h);
}
__device__ __forceinline__ int udot4(uint32_t a, uint32_t b, int acc) {
#if __has_builtin(__builtin_amdgcn_udot4)
    return __builtin_amdgcn_udot4(a, b, acc, false);
#else
    return acc + (int)((a & 255u) * (b & 255u))
               + (int)(((a >> 8) & 255u) * ((b >> 8) & 255u))
               + (int)(((a >> 16) & 255u) * ((b >> 16) & 255u))
               + (int)((a >> 24) * (b >> 24));
#endif
}

// ---------------- GEMM v2: MFMA f16 16x16x32, 128x128 tile ----------------
// Double-buffered LDS, ONE barrier per K-iter. Measured round 5: cut the
// non-scan residual from ~148us to ~34us. Do not touch.
__global__ __launch_bounds__(256) void gemm_mfma(
    const float* __restrict__ A, const float* __restrict__ W,
    const float* __restrict__ bias, float* __restrict__ C)
{
    const int K = HID, N = VOC;
    __shared__ _Float16 As[2][128][40];
    __shared__ _Float16 Ws[2][128][40];
    int tid  = threadIdx.x;
    int wv   = tid >> 6;
    int lane = tid & 63;
    int wy = wv >> 1, wx = wv & 1;
    int quad = lane >> 4, l16 = lane & 15;
    int row0 = blockIdx.y << 7;
    int col0 = blockIdx.x << 7;

    v4f acc[4][4] = {};

    int sr = tid >> 1;
    int sk = (tid & 1) << 4;
    const float* ap = A + (size_t)(row0 + sr) * K + sk;
    const float* wp = W + (size_t)(col0 + sr) * K + sk;

    float4 a0 = *(const float4*)(ap);
    float4 a1 = *(const float4*)(ap + 4);
    float4 a2 = *(const float4*)(ap + 8);
    float4 a3 = *(const float4*)(ap + 12);
    float4 w0 = *(const float4*)(wp);
    float4 w1 = *(const float4*)(wp + 4);
    float4 w2 = *(const float4*)(wp + 8);
    float4 w3 = *(const float4*)(wp + 12);
    {
        uint32_t* ad = (uint32_t*)&As[0][sr][sk];
        ad[0] = pack_pkrtz(a0.x, a0.y); ad[1] = pack_pkrtz(a0.z, a0.w);
        ad[2] = pack_pkrtz(a1.x, a1.y); ad[3] = pack_pkrtz(a1.z, a1.w);
        ad[4] = pack_pkrtz(a2.x, a2.y); ad[5] = pack_pkrtz(a2.z, a2.w);
        ad[6] = pack_pkrtz(a3.x, a3.y); ad[7] = pack_pkrtz(a3.z, a3.w);
        uint32_t* wd = (uint32_t*)&Ws[0][sr][sk];
        wd[0] = pack_pkrtz(w0.x, w0.y); wd[1] = pack_pkrtz(w0.z, w0.w);
        wd[2] = pack_pkrtz(w1.x, w1.y); wd[3] = pack_pkrtz(w1.z, w1.w);
        wd[4] = pack_pkrtz(w2.x, w2.y); wd[5] = pack_pkrtz(w2.z, w2.w);
        wd[6] = pack_pkrtz(w3.x, w3.y); wd[7] = pack_pkrtz(w3.z, w3.w);
    }
    __syncthreads();

    const int NIT = K / 32;             // 16
    for (int i = 0; i < NIT; ++i) {
        int cur = i & 1, nxt = cur ^ 1;
        if (i + 1 < NIT) {
            const float* apn = ap + (i + 1) * 32;
            const float* wpn = wp + (i + 1) * 32;
            a0 = *(const float4*)(apn);
            a1 = *(const float4*)(apn + 4);
            a2 = *(const float4*)(apn + 8);
            a3 = *(const float4*)(apn + 12);
            w0 = *(const float4*)(wpn);
            w1 = *(const float4*)(wpn + 4);
            w2 = *(const float4*)(wpn + 8);
            w3 = *(const float4*)(wpn + 12);
        }
        v8h af[4], bf[4];
        #pragma unroll
        for (int r = 0; r < 4; ++r)
            af[r] = *(const v8h*)&As[cur][wy * 64 + r * 16 + l16][quad * 8];
        #pragma unroll
        for (int r = 0; r < 4; ++r)
            bf[r] = *(const v8h*)&Ws[cur][wx * 64 + r * 16 + l16][quad * 8];
        #pragma unroll
        for (int r = 0; r < 4; ++r)
            #pragma unroll
            for (int j = 0; j < 4; ++j)
                acc[r][j] = __builtin_amdgcn_mfma_f32_16x16x32_f16(af[r], bf[j], acc[r][j], 0, 0, 0);
        if (i + 1 < NIT) {
            uint32_t* ad = (uint32_t*)&As[nxt][sr][sk];
            ad[0] = pack_pkrtz(a0.x, a0.y); ad[1] = pack_pkrtz(a0.z, a0.w);
            ad[2] = pack_pkrtz(a1.x, a1.y); ad[3] = pack_pkrtz(a1.z, a1.w);
            ad[4] = pack_pkrtz(a2.x, a2.y); ad[5] = pack_pkrtz(a2.z, a2.w);
            ad[6] = pack_pkrtz(a3.x, a3.y); ad[7] = pack_pkrtz(a3.z, a3.w);
            uint32_t* wd = (uint32_t*)&Ws[nxt][sr][sk];
            wd[0] = pack_pkrtz(w0.x, w0.y); wd[1] = pack_pkrtz(w0.z, w0.w);
            wd[2] = pack_pkrtz(w1.x, w1.y); wd[3] = pack_pkrtz(w1.z, w1.w);
            wd[4] = pack_pkrtz(w2.x, w2.y); wd[5] = pack_pkrtz(w2.z, w2.w);
            wd[6] = pack_pkrtz(w3.x, w3.y); wd[7] = pack_pkrtz(w3.z, w3.w);
        }
        __syncthreads();
    }
    #pragma unroll
    for (int i = 0; i < 4; ++i) {
        #pragma unroll
        for (int j = 0; j < 4; ++j) {
            int ccol = col0 + wx * 64 + j * 16 + l16;
            float bb = bias[ccol];
            #pragma unroll
            for (int r = 0; r < 4; ++r) {
                int rrow = row0 + wy * 64 + i * 16 + quad * 4 + r;
                C[(size_t)rrow * N + ccol] = acc[i][j][r] + bb;
            }
        }
    }
}

// ---------------- persistent CRF scan v18: fan-in 4 via 1024-thread blocks ----------------
// Rounds 9-11: fan-in-4 at 512 threads needs 128 E-words/thread, which the
// compiler refuses to register-allocate (3 attempts, identical scratch spill).
// v18 keeps the PROVEN per-thread budget (64 E-words, v16's exact shape) and
// doubles the block instead: grid (32 batch, 4 colblock), 1024 thr = 16 waves.
//  - Wave w covers v-chunk [w*64, w*64+64) -> producer block = w>>2, fan-in 4.
//  - Lanes 0-15 load 16B each (256B poll chunk per wave).
//  - Each thread owns 4 cols (lane + 64q); EregA..D[16] = 64 u32 total.
//  - Compute: 16 readlane + 64 udot4 (v16: 32 + 64). Finalize sums 16 waves.
//  - Sync mechanism byte-identical to v12/v16 (tag nibble, ping-pong, one
//    barrier/step). Every block polls all 4 producers (4 waves each) -> the
//    v16 skew/overwrite proof carries unchanged.
__global__ __launch_bounds__(1024, 4) void crf_scan(
    const float* __restrict__ logits, float* __restrict__ Za, float* __restrict__ Zb,
    float* __restrict__ Zfin,
    const float* __restrict__ trans, const int* __restrict__ lengths)
{
    __shared__ float Sred[2][16][64][5];  // [parity][wave][lane][4 cols + pad]
    __shared__ float Mred[2][16];         // [parity][wave] chunk maxes
    int tid  = threadIdx.x;
    int w    = tid >> 6;               // 0..15
    int lane = tid & 63;
    int b    = blockIdx.x;             // batch (group)
    int k    = blockIdx.y;             // column block: cols [k*256, k*256+256)

    int len = lengths[b];

    // E slices in VGPRs (64 u32/thread, v16-proven budget):
    // EregQ[j] = u8x4 of exp(trans[w*64+4j+kk][cq])*196, cq = k*256+lane+64*q
    uint32_t EregA[16], EregB[16], EregC[16], EregD[16];
    {
        const float* tc = trans + (k << 8) + lane;
        #pragma unroll
        for (int j = 0; j < 16; ++j) {
            int v0 = (w << 6) + (j << 2);
            #pragma unroll
            for (int q = 0; q < 4; ++q) {
                const float* tq = tc + (q << 6);
                float a0 = __expf(tq[(size_t)(v0 + 0) << 10]) * 196.f;
                float a1 = __expf(tq[(size_t)(v0 + 1) << 10]) * 196.f;
                float a2 = __expf(tq[(size_t)(v0 + 2) << 10]) * 196.f;
                float a3 = __expf(tq[(size_t)(v0 + 3) << 10]) * 196.f;
                uint32_t q0 = (uint32_t)__float2uint_rn(fminf(a0, 255.f));
                uint32_t q1 = (uint32_t)__float2uint_rn(fminf(a1, 255.f));
                uint32_t q2 = (uint32_t)__float2uint_rn(fminf(a2, 255.f));
                uint32_t q3 = (uint32_t)__float2uint_rn(fminf(a3, 255.f));
                uint32_t pk = q0 | (q1 << 8) | (q2 << 16) | (q3 << 24);
                if      (q == 0) EregA[j] = pk;
                else if (q == 1) EregB[j] = pk;
                else if (q == 2) EregC[j] = pk;
                else             EregD[j] = pk;
            }
        }
    }

    // prologue: len==1 freezes at Z0 = logits[0]; else prefetch fin for t=1
    float finv = 0.f;
    if (tid < 256) {
        int c = (k << 8) + tid;
        if (len == 1) Zfin[(size_t)b * VOC + c] = logits[(size_t)b * VOC + c];
        else          finv = logits[(size_t)(NB + b) * VOC + c];   // logits[t=1]
    }

    const bool loader = (lane < 16);
    // loader lane covers v = w*64 + lane*4 .. +3 (producer block = w>>2)
    const size_t zoff = (size_t)b * VOC + (size_t)((w << 6) + (lane << 2));
    float2 zlo = {0.f, 0.f}, zhi = {0.f, 0.f};

    for (int t = 1; t < len; ++t) {
        int par = t & 1;
        // (A) stage Z_{t-1}: poll self-validating tagged words, sleep backoff,
        //     bounded budget (anti-hang diagnostic; never hit in normal runs)
        if (t == 1) {
            if (loader) {
                const float* zp = logits + zoff;    // Z0 = logits[0], kernel-ordered
                zlo = *(const float2*)zp;
                zhi = *(const float2*)(zp + 2);
            }
        } else if (loader) {
            const float* zp = ((t & 1) ? Zb : Za) + zoff;   // src = dst(t-1)
            unsigned tg = 8u | (unsigned)((t - 1) & 7);
            int budget = 1 << 16;
            for (;;) {
                float2 a = zload2(zp);
                float2 bb = zload2(zp + 2);
                unsigned x0 = __builtin_bit_cast(unsigned, a.x) & 15u;
                unsigned x1 = __builtin_bit_cast(unsigned, a.y) & 15u;
                unsigned x2 = __builtin_bit_cast(unsigned, bb.x) & 15u;
                unsigned x3 = __builtin_bit_cast(unsigned, bb.y) & 15u;
                if (((x0 ^ tg) | (x1 ^ tg) | (x2 ^ tg) | (x3 ^ tg)) == 0u) {
                    zlo = a; zhi = bb; break;
                }
                if (--budget == 0) { zlo = a; zhi = bb; break; }   // diagnostic
                __builtin_amdgcn_s_sleep(1);
            }
        }

        // (B) chunk max over 64 v (16 loader lanes x 4) + quantize
        float m = loader ? fmaxf(fmaxf(zlo.x, zlo.y), fmaxf(zhi.x, zhi.y)) : -3.0e38f;
        #pragma unroll
        for (int off = 8; off; off >>= 1) m = fmaxf(m, __shfl_xor(m, off));
        if (lane == 0) Mred[par][w] = m;
        uint32_t pp = 0;
        if (loader) {
            uint32_t q0 = (uint32_t)__float2uint_rn(__expf(zlo.x - m) * 255.f);
            uint32_t q1 = (uint32_t)__float2uint_rn(__expf(zlo.y - m) * 255.f);
            uint32_t q2 = (uint32_t)__float2uint_rn(__expf(zhi.x - m) * 255.f);
            uint32_t q3 = (uint32_t)__float2uint_rn(__expf(zhi.y - m) * 255.f);
            pp = q0 | (q1 << 8) | (q2 << 16) | (q3 << 24);
        }

        // (C) 16 v4-rows x 4 cols, E from registers; p broadcast via readlane
        int acc0 = 0, acc1 = 0, acc2 = 0, acc3 = 0;
        #pragma unroll
        for (int j = 0; j < 16; j += 2) {
            uint32_t s0 = (uint32_t)__builtin_amdgcn_readlane((int)pp, j);
            uint32_t s1 = (uint32_t)__builtin_amdgcn_readlane((int)pp, j + 1);
            acc0 = udot4(EregA[j], s0, acc0);
            acc1 = udot4(EregB[j], s0, acc1);
            acc2 = udot4(EregC[j], s0, acc2);
            acc3 = udot4(EregD[j], s0, acc3);
            acc0 = udot4(EregA[j + 1], s1, acc0);
            acc1 = udot4(EregB[j + 1], s1, acc1);
            acc2 = udot4(EregC[j + 1], s1, acc2);
            acc3 = udot4(EregD[j + 1], s1, acc3);
        }
        Sred[par][w][lane][0] = (float)acc0;
        Sred[par][w][lane][1] = (float)acc1;
        Sred[par][w][lane][2] = (float)acc2;
        Sred[par][w][lane][3] = (float)acc3;
        __syncthreads();                  // the ONLY barrier per step

        // (D) finalize + tagged store + fin(t+1) prefetch
        if (tid < 256) {
            float M = Mred[par][0];
            #pragma unroll
            for (int ww = 1; ww < 16; ++ww) M = fmaxf(M, Mred[par][ww]);
            int l = tid & 63, hc = tid >> 6;
            float S = 0.f;
            #pragma unroll
            for (int ww = 0; ww < 16; ++ww)
                S += __expf(Mred[par][ww] - M) * Sred[par][ww][l][hc];
            int c = (k << 8) + tid;
            float outv = finv + M + __logf(S * (1.0f / (255.f * 196.f)));
            if (t < len - 1) {
                float* dst = (t & 1) ? Za : Zb;
                unsigned ub = (__builtin_bit_cast(unsigned, outv) & ~15u)
                            | 8u | (unsigned)(t & 7);
                zstore(&dst[(size_t)b * VOC + c], __builtin_bit_cast(float, ub));
                finv = logits[((size_t)(t + 1) * NB + b) * VOC + c];
            } else {
                Zfin[(size_t)b * VOC + c] = outv;   // final value, untagged
            }
        }
        // next iteration writes parity^1 -> no trailing barrier needed
    }
}

// ---------------- epilogue: one block per batch, atomicAdd combine ----------------
__global__ __launch_bounds__(256) void crf_finish2(
    const float* __restrict__ Zfin, const float* __restrict__ logits,
    const float* __restrict__ trans, const int* __restrict__ targets,
    const int* __restrict__ lengths, float* __restrict__ out)
{
    __shared__ float redm[4], reds[4], reda[4];
    int b = blockIdx.x;
    int tid = threadIdx.x;
    int lane = tid & 63, wv = tid >> 6;
    const float* zr = Zfin + (size_t)b * VOC;

    float m = -1e30f;
    #pragma unroll
    for (int i = 0; i < 4; ++i) m = fmaxf(m, zr[tid + (i << 8)]);
    #pragma unroll
    for (int off = 32; off; off >>= 1) m = fmaxf(m, __shfl_xor(m, off));
    if (lane == 0) redm[wv] = m;
    __syncthreads();
    m = fmaxf(fmaxf(redm[0], redm[1]), fmaxf(redm[2], redm[3]));

    float s = 0.f;
    #pragma unroll
    for (int i = 0; i < 4; ++i) s += __expf(zr[tid + (i << 8)] - m);
    #pragma unroll
    for (int off = 32; off; off >>= 1) s += __shfl_xor(s, off);
    if (lane == 0) reds[wv] = s;

    int len = lengths[b];
    float acc = 0.f;
    int t = tid;
    if (t < len) {
        int tg = targets[t * NB + b];
        acc = logits[((size_t)t * NB + b) * VOC + tg];
        if (t >= 1) acc += trans[(size_t)targets[(t - 1) * NB + b] * VOC + tg];
    }
    #pragma unroll
    for (int off = 32; off; off >>= 1) acc += __shfl_xor(acc, off);
    if (lane == 0) reda[wv] = acc;
    __syncthreads();

    if (tid == 0) {
        float S = reds[0] + reds[1] + reds[2] + reds[3];
        float logZ = m + __logf(S);
        float score = reda[0] + reda[1] + reda[2] + reda[3];
        atomicAdd(out, (logZ - score) * (1.0f / NB));
    }
}

extern "C" void kernel_launch(void* const* d_in, const int* in_sizes, int n_in,
                              void* d_out, int out_size, void* d_ws, size_t ws_size,
                              hipStream_t stream)
{
    const float* enc   = (const float*)d_in[0];
    const float* W     = (const float*)d_in[1];
    const float* bias  = (const float*)d_in[2];
    const float* trans = (const float*)d_in[3];
    const int* targets = (const int*)d_in[4];
    const int* lengths = (const int*)d_in[5];
    float* out = (float*)d_out;

    // ws: logits 33.5MB | Za 128KB | Zb 128KB | Zfin 128KB
    float* ws     = (float*)d_ws;
    float* logits = ws;
    float* Za     = logits + (size_t)TLEN * NB * VOC;
    float* Zb     = Za + (size_t)NB * VOC;
    float* Zfin   = Zb + (size_t)NB * VOC;

    // tags live in Z words: zero-init (nibble 0 unreachable as a tag; also
    // clears stale tag-bearing data from a previous run of this graph)
    (void)hipMemsetAsync(Za, 0, 2 * (size_t)NB * VOC * sizeof(float), stream);
    (void)hipMemsetAsync(out, 0, sizeof(float), stream);
    gemm_mfma<<<dim3(VOC / 128, TLEN * NB / 128), 256, 0, stream>>>(enc, W, bias, logits);
    crf_scan<<<dim3(NB, 4), 1024, 0, stream>>>(logits, Za, Zb, Zfin, trans, lengths);
    crf_finish2<<<NB, 256, 0, stream>>>(Zfin, logits, trans, targets, lengths, out);
}

// Round 13
// 530.464 us; speedup vs baseline: 1.4248x; 1.4022x over previous
//
#include <hip/hip_runtime.h>
#include <math.h>
#include <stdint.h>

#define TLEN 256
#define NB   32
#define HID  512
#define VOC  1024

typedef __attribute__((ext_vector_type(2))) __fp16  pk16_t;
typedef __attribute__((ext_vector_type(8))) _Float16 v8h;
typedef __attribute__((ext_vector_type(4))) float    v4f;

// ---- device-coherent (agent-scope) Z accessors ----
__device__ __forceinline__ float2 zload2(const float* p) {
    unsigned long long u = __hip_atomic_load((const unsigned long long*)p,
                                             __ATOMIC_RELAXED, __HIP_MEMORY_SCOPE_AGENT);
    union { unsigned long long u; float2 f; } c; c.u = u; return c.f;
}
__device__ __forceinline__ void zstore(float* p, float v) {
    __hip_atomic_store(p, v, __ATOMIC_RELAXED, __HIP_MEMORY_SCOPE_AGENT);
}
__device__ __forceinline__ uint32_t pack_pkrtz(float a, float b) {
    pk16_t h = __builtin_amdgcn_cvt_pkrtz(a, b);
    return __builtin_bit_cast(uint32_t, h);
}
__device__ __forceinline__ int udot4(uint32_t a, uint32_t b, int acc) {
#if __has_builtin(__builtin_amdgcn_udot4)
    return __builtin_amdgcn_udot4(a, b, acc, false);
#else
    return acc + (int)((a & 255u) * (b & 255u))
               + (int)(((a >> 8) & 255u) * ((b >> 8) & 255u))
               + (int)(((a >> 16) & 255u) * ((b >> 16) & 255u))
               + (int)((a >> 24) * (b >> 24));
#endif
}

// ---------------- GEMM v2: MFMA f16 16x16x32, 128x128 tile ----------------
// Double-buffered LDS, ONE barrier per K-iter. Measured round 5: cut the
// non-scan residual from ~148us to ~34us. Do not touch.
__global__ __launch_bounds__(256) void gemm_mfma(
    const float* __restrict__ A, const float* __restrict__ W,
    const float* __restrict__ bias, float* __restrict__ C)
{
    const int K = HID, N = VOC;
    __shared__ _Float16 As[2][128][40];
    __shared__ _Float16 Ws[2][128][40];
    int tid  = threadIdx.x;
    int wv   = tid >> 6;
    int lane = tid & 63;
    int wy = wv >> 1, wx = wv & 1;
    int quad = lane >> 4, l16 = lane & 15;
    int row0 = blockIdx.y << 7;
    int col0 = blockIdx.x << 7;

    v4f acc[4][4] = {};

    int sr = tid >> 1;
    int sk = (tid & 1) << 4;
    const float* ap = A + (size_t)(row0 + sr) * K + sk;
    const float* wp = W + (size_t)(col0 + sr) * K + sk;

    float4 a0 = *(const float4*)(ap);
    float4 a1 = *(const float4*)(ap + 4);
    float4 a2 = *(const float4*)(ap + 8);
    float4 a3 = *(const float4*)(ap + 12);
    float4 w0 = *(const float4*)(wp);
    float4 w1 = *(const float4*)(wp + 4);
    float4 w2 = *(const float4*)(wp + 8);
    float4 w3 = *(const float4*)(wp + 12);
    {
        uint32_t* ad = (uint32_t*)&As[0][sr][sk];
        ad[0] = pack_pkrtz(a0.x, a0.y); ad[1] = pack_pkrtz(a0.z, a0.w);
        ad[2] = pack_pkrtz(a1.x, a1.y); ad[3] = pack_pkrtz(a1.z, a1.w);
        ad[4] = pack_pkrtz(a2.x, a2.y); ad[5] = pack_pkrtz(a2.z, a2.w);
        ad[6] = pack_pkrtz(a3.x, a3.y); ad[7] = pack_pkrtz(a3.z, a3.w);
        uint32_t* wd = (uint32_t*)&Ws[0][sr][sk];
        wd[0] = pack_pkrtz(w0.x, w0.y); wd[1] = pack_pkrtz(w0.z, w0.w);
        wd[2] = pack_pkrtz(w1.x, w1.y); wd[3] = pack_pkrtz(w1.z, w1.w);
        wd[4] = pack_pkrtz(w2.x, w2.y); wd[5] = pack_pkrtz(w2.z, w2.w);
        wd[6] = pack_pkrtz(w3.x, w3.y); wd[7] = pack_pkrtz(w3.z, w3.w);
    }
    __syncthreads();

    const int NIT = K / 32;             // 16
    for (int i = 0; i < NIT; ++i) {
        int cur = i & 1, nxt = cur ^ 1;
        if (i + 1 < NIT) {
            const float* apn = ap + (i + 1) * 32;
            const float* wpn = wp + (i + 1) * 32;
            a0 = *(const float4*)(apn);
            a1 = *(const float4*)(apn + 4);
            a2 = *(const float4*)(apn + 8);
            a3 = *(const float4*)(apn + 12);
            w0 = *(const float4*)(wpn);
            w1 = *(const float4*)(wpn + 4);
            w2 = *(const float4*)(wpn + 8);
            w3 = *(const float4*)(wpn + 12);
        }
        v8h af[4], bf[4];
        #pragma unroll
        for (int r = 0; r < 4; ++r)
            af[r] = *(const v8h*)&As[cur][wy * 64 + r * 16 + l16][quad * 8];
        #pragma unroll
        for (int r = 0; r < 4; ++r)
            bf[r] = *(const v8h*)&Ws[cur][wx * 64 + r * 16 + l16][quad * 8];
        #pragma unroll
        for (int r = 0; r < 4; ++r)
            #pragma unroll
            for (int j = 0; j < 4; ++j)
                acc[r][j] = __builtin_amdgcn_mfma_f32_16x16x32_f16(af[r], bf[j], acc[r][j], 0, 0, 0);
        if (i + 1 < NIT) {
            uint32_t* ad = (uint32_t*)&As[nxt][sr][sk];
            ad[0] = pack_pkrtz(a0.x, a0.y); ad[1] = pack_pkrtz(a0.z, a0.w);
            ad[2] = pack_pkrtz(a1.x, a1.y); ad[3] = pack_pkrtz(a1.z, a1.w);
            ad[4] = pack_pkrtz(a2.x, a2.y); ad[5] = pack_pkrtz(a2.z, a2.w);
            ad[6] = pack_pkrtz(a3.x, a3.y); ad[7] = pack_pkrtz(a3.z, a3.w);
            uint32_t* wd = (uint32_t*)&Ws[nxt][sr][sk];
            wd[0] = pack_pkrtz(w0.x, w0.y); wd[1] = pack_pkrtz(w0.z, w0.w);
            wd[2] = pack_pkrtz(w1.x, w1.y); wd[3] = pack_pkrtz(w1.z, w1.w);
            wd[4] = pack_pkrtz(w2.x, w2.y); wd[5] = pack_pkrtz(w2.z, w2.w);
            wd[6] = pack_pkrtz(w3.x, w3.y); wd[7] = pack_pkrtz(w3.z, w3.w);
        }
        __syncthreads();
    }
    #pragma unroll
    for (int i = 0; i < 4; ++i) {
        #pragma unroll
        for (int j = 0; j < 4; ++j) {
            int ccol = col0 + wx * 64 + j * 16 + l16;
            float bb = bias[ccol];
            #pragma unroll
            for (int r = 0; r < 4; ++r) {
                int rrow = row0 + wy * 64 + i * 16 + quad * 4 + r;
                C[(size_t)rrow * N + ccol] = acc[i][j][r] + bb;
            }
        }
    }
}

// ---------------- persistent CRF scan v16 (round-7 measured 443us) ----------------
// Grid (32 batch, 8 colblock), 512 thr = 8 waves. Best measured scan config:
//  - Each group = ONE batch; block owns 128 columns; wave w owns v-chunk
//    [w*128, w*128+128), produced by colblock w -> fan-in 8.
//  - Ereg[64] per thread: the ONLY E-layout this toolchain register-allocates
//    cleanly (VGPR 128, zero spill). Fan-in-4 variants (128 E-words or
//    1024-thr blocks) spilled to scratch in 4/4 attempts (rounds 9-12) —
//    retired. Do not revisit without disasm access.
//  - Tagged data-flow (nibble 8|(t&7) in Z mantissa low bits), ping-pong
//    Za/Zb, ONE barrier/step, s_sleep(1) poll backoff.
__global__ __launch_bounds__(512) void crf_scan(
    const float* __restrict__ logits, float* __restrict__ Za, float* __restrict__ Zb,
    float* __restrict__ Zfin,
    const float* __restrict__ trans, const int* __restrict__ lengths)
{
    __shared__ float Sred[2][8][64][3];   // [parity][wave][lane][colhalf]+pad
    __shared__ float Mred[2][8];          // [parity][wave] chunk maxes
    int tid  = threadIdx.x;
    int w    = tid >> 6;
    int lane = tid & 63;
    int b    = blockIdx.x;             // batch (group)
    int k    = blockIdx.y;             // column block: cols [k*128, k*128+128)

    int len = lengths[b];

    // E slice in VGPRs: Ereg[j] = u8x4 of exp(trans[128w+4j+kk][c0])*196
    // for own col c0 = k*128+lane; Ereg[j+32] same for c1 = c0+64.
    uint32_t Ereg[64];
    {
        const float* tc0 = trans + (k << 7) + lane;
        const float* tc1 = tc0 + 64;
        #pragma unroll
        for (int j = 0; j < 32; ++j) {
            int v0 = (w << 7) + (j << 2);
            float a0 = __expf(tc0[(size_t)(v0 + 0) << 10]) * 196.f;
            float a1 = __expf(tc0[(size_t)(v0 + 1) << 10]) * 196.f;
            float a2 = __expf(tc0[(size_t)(v0 + 2) << 10]) * 196.f;
            float a3 = __expf(tc0[(size_t)(v0 + 3) << 10]) * 196.f;
            uint32_t q0 = (uint32_t)__float2uint_rn(fminf(a0, 255.f));
            uint32_t q1 = (uint32_t)__float2uint_rn(fminf(a1, 255.f));
            uint32_t q2 = (uint32_t)__float2uint_rn(fminf(a2, 255.f));
            uint32_t q3 = (uint32_t)__float2uint_rn(fminf(a3, 255.f));
            Ereg[j] = q0 | (q1 << 8) | (q2 << 16) | (q3 << 24);
            float b0 = __expf(tc1[(size_t)(v0 + 0) << 10]) * 196.f;
            float b1 = __expf(tc1[(size_t)(v0 + 1) << 10]) * 196.f;
            float b2 = __expf(tc1[(size_t)(v0 + 2) << 10]) * 196.f;
            float b3 = __expf(tc1[(size_t)(v0 + 3) << 10]) * 196.f;
            uint32_t r0 = (uint32_t)__float2uint_rn(fminf(b0, 255.f));
            uint32_t r1 = (uint32_t)__float2uint_rn(fminf(b1, 255.f));
            uint32_t r2 = (uint32_t)__float2uint_rn(fminf(b2, 255.f));
            uint32_t r3 = (uint32_t)__float2uint_rn(fminf(b3, 255.f));
            Ereg[j + 32] = r0 | (r1 << 8) | (r2 << 16) | (r3 << 24);
        }
    }

    // prologue: len==1 freezes at Z0 = logits[0]; else prefetch fin for t=1
    float finv = 0.f;
    if (tid < 128) {
        int c = (k << 7) + tid;
        if (len == 1) Zfin[(size_t)b * VOC + c] = logits[(size_t)b * VOC + c];
        else          finv = logits[(size_t)(NB + b) * VOC + c];   // logits[t=1]
    }

    const bool loader = (lane < 32);
    // loader lane covers v = w*128 + lane*4 .. +3 (producer block = colblock w)
    const size_t zoff = (size_t)b * VOC + (size_t)((w << 7) + (lane << 2));
    float2 zlo = {0.f, 0.f}, zhi = {0.f, 0.f};

    for (int t = 1; t < len; ++t) {
        int par = t & 1;
        // (A) stage Z_{t-1}: poll self-validating tagged words, sleep backoff
        if (t == 1) {
            if (loader) {
                const float* zp = logits + zoff;    // Z0 = logits[0], kernel-ordered
                zlo = *(const float2*)zp;
                zhi = *(const float2*)(zp + 2);
            }
        } else if (loader) {
            const float* zp = ((t & 1) ? Zb : Za) + zoff;   // src = dst(t-1)
            unsigned tg = 8u | (unsigned)((t - 1) & 7);
            for (;;) {
                float2 a = zload2(zp);
                float2 bb = zload2(zp + 2);
                unsigned x0 = __builtin_bit_cast(unsigned, a.x) & 15u;
                unsigned x1 = __builtin_bit_cast(unsigned, a.y) & 15u;
                unsigned x2 = __builtin_bit_cast(unsigned, bb.x) & 15u;
                unsigned x3 = __builtin_bit_cast(unsigned, bb.y) & 15u;
                if (((x0 ^ tg) | (x1 ^ tg) | (x2 ^ tg) | (x3 ^ tg)) == 0u) {
                    zlo = a; zhi = bb; break;
                }
                __builtin_amdgcn_s_sleep(1);
            }
        }

        // (B) chunk max over 128 v (32 loader lanes x 4) + quantize
        float m = loader ? fmaxf(fmaxf(zlo.x, zlo.y), fmaxf(zhi.x, zhi.y)) : -3.0e38f;
        #pragma unroll
        for (int off = 16; off; off >>= 1) m = fmaxf(m, __shfl_xor(m, off));
        if (lane == 0) Mred[par][w] = m;
        uint32_t pp = 0;
        if (loader) {
            uint32_t q0 = (uint32_t)__float2uint_rn(__expf(zlo.x - m) * 255.f);
            uint32_t q1 = (uint32_t)__float2uint_rn(__expf(zlo.y - m) * 255.f);
            uint32_t q2 = (uint32_t)__float2uint_rn(__expf(zhi.x - m) * 255.f);
            uint32_t q3 = (uint32_t)__float2uint_rn(__expf(zhi.y - m) * 255.f);
            pp = q0 | (q1 << 8) | (q2 << 16) | (q3 << 24);
        }

        // (C) 32 v4-rows, E from registers; p broadcast lane->SGPR via readlane
        int acc0 = 0, acc1 = 0;
        #pragma unroll
        for (int j = 0; j < 32; j += 2) {
            uint32_t s0 = (uint32_t)__builtin_amdgcn_readlane((int)pp, j);
            uint32_t s1 = (uint32_t)__builtin_amdgcn_readlane((int)pp, j + 1);
            acc0 = udot4(Ereg[j], s0, acc0);
            acc1 = udot4(Ereg[j + 32], s0, acc1);
            acc0 = udot4(Ereg[j + 1], s1, acc0);
            acc1 = udot4(Ereg[j + 33], s1, acc1);
        }
        Sred[par][w][lane][0] = (float)acc0;
        Sred[par][w][lane][1] = (float)acc1;
        __syncthreads();                  // the ONLY barrier per step

        // (D) finalize + tagged store + fin(t+1) prefetch
        if (tid < 128) {
            float M = Mred[par][0];
            #pragma unroll
            for (int ww = 1; ww < 8; ++ww) M = fmaxf(M, Mred[par][ww]);
            int l = tid & 63, hc = tid >> 6;
            float S = 0.f;
            #pragma unroll
            for (int ww = 0; ww < 8; ++ww)
                S += __expf(Mred[par][ww] - M) * Sred[par][ww][l][hc];
            int c = (k << 7) + tid;
            float outv = finv + M + __logf(S * (1.0f / (255.f * 196.f)));
            if (t < len - 1) {
                float* dst = (t & 1) ? Za : Zb;
                unsigned ub = (__builtin_bit_cast(unsigned, outv) & ~15u)
                            | 8u | (unsigned)(t & 7);
                zstore(&dst[(size_t)b * VOC + c], __builtin_bit_cast(float, ub));
                finv = logits[((size_t)(t + 1) * NB + b) * VOC + c];
            } else {
                Zfin[(size_t)b * VOC + c] = outv;   // final value, untagged
            }
        }
        // next iteration writes parity^1 -> no trailing barrier needed
    }
}

// ---------------- epilogue: one block per batch, atomicAdd combine ----------------
__global__ __launch_bounds__(256) void crf_finish2(
    const float* __restrict__ Zfin, const float* __restrict__ logits,
    const float* __restrict__ trans, const int* __restrict__ targets,
    const int* __restrict__ lengths, float* __restrict__ out)
{
    __shared__ float redm[4], reds[4], reda[4];
    int b = blockIdx.x;
    int tid = threadIdx.x;
    int lane = tid & 63, wv = tid >> 6;
    const float* zr = Zfin + (size_t)b * VOC;

    float m = -1e30f;
    #pragma unroll
    for (int i = 0; i < 4; ++i) m = fmaxf(m, zr[tid + (i << 8)]);
    #pragma unroll
    for (int off = 32; off; off >>= 1) m = fmaxf(m, __shfl_xor(m, off));
    if (lane == 0) redm[wv] = m;
    __syncthreads();
    m = fmaxf(fmaxf(redm[0], redm[1]), fmaxf(redm[2], redm[3]));

    float s = 0.f;
    #pragma unroll
    for (int i = 0; i < 4; ++i) s += __expf(zr[tid + (i << 8)] - m);
    #pragma unroll
    for (int off = 32; off; off >>= 1) s += __shfl_xor(s, off);
    if (lane == 0) reds[wv] = s;

    int len = lengths[b];
    float acc = 0.f;
    int t = tid;
    if (t < len) {
        int tg = targets[t * NB + b];
        acc = logits[((size_t)t * NB + b) * VOC + tg];
        if (t >= 1) acc += trans[(size_t)targets[(t - 1) * NB + b] * VOC + tg];
    }
    #pragma unroll
    for (int off = 32; off; off >>= 1) acc += __shfl_xor(acc, off);
    if (lane == 0) reda[wv] = acc;
    __syncthreads();

    if (tid == 0) {
        float S = reds[0] + reds[1] + reds[2] + reds[3];
        float logZ = m + __logf(S);
        float score = reda[0] + reda[1] + reda[2] + reda[3];
        atomicAdd(out, (logZ - score) * (1.0f / NB));
    }
}

extern "C" void kernel_launch(void* const* d_in, const int* in_sizes, int n_in,
                              void* d_out, int out_size, void* d_ws, size_t ws_size,
                              hipStream_t stream)
{
    const float* enc   = (const float*)d_in[0];
    const float* W     = (const float*)d_in[1];
    const float* bias  = (const float*)d_in[2];
    const float* trans = (const float*)d_in[3];
    const int* targets = (const int*)d_in[4];
    const int* lengths = (const int*)d_in[5];
    float* out = (float*)d_out;

    // ws: logits 33.5MB | Za 128KB | Zb 128KB | Zfin 128KB
    float* ws     = (float*)d_ws;
    float* logits = ws;
    float* Za     = logits + (size_t)TLEN * NB * VOC;
    float* Zb     = Za + (size_t)NB * VOC;
    float* Zfin   = Zb + (size_t)NB * VOC;

    // tags live in Z words: zero-init (nibble 0 unreachable as a tag; also
    // clears stale tag-bearing data from a previous run of this graph)
    (void)hipMemsetAsync(Za, 0, 2 * (size_t)NB * VOC * sizeof(float), stream);
    (void)hipMemsetAsync(out, 0, sizeof(float), stream);
    gemm_mfma<<<dim3(VOC / 128, TLEN * NB / 128), 256, 0, stream>>>(enc, W, bias, logits);
    crf_scan<<<dim3(NB, 8), 512, 0, stream>>>(logits, Za, Zb, Zfin, trans, lengths);
    crf_finish2<<<NB, 256, 0, stream>>>(Zfin, logits, trans, targets, lengths, out);
}